// Round 9
// baseline (208.228 us; speedup 1.0000x reference)
//
#include <hip/hip_runtime.h>

// NonLocalBlock B=8, L=2048, C=512, CI=256 (fp32 in/out).
// Round 15:
//   - score_softmax REWRITE: batch-parallel waves. 512 thr / 8 waves, same
//     64x64 (l,m) tile. Batches in 2 groups of 4 resident in LDS at once;
//     wave w computes batch w&3 on n-half w>>2. Stages 16 -> 8 (each 2x
//     bigger: 8 gload16/thread), LDS 66.5 KB -> 2 blocks/CU = 16 waves/CU
//     (same as r13) with 2x in-flight per wave. sv halves to 32 u32 (no
//     spill headroom, launch_bounds(512,4) caps VGPR 128). Softmax via
//     65-padded LDS exchange (2-way conflicts only), coalesced ATT write.
//     All __syncthreads (no raw-barrier hang risk, r11/r12 lesson).
//   - r14's 32x64 TLP attack REVERTED (VGPR-48 spill: WRITE +12MB; 1.5x
//     staging traffic; occupancy 39% yet slower -> TLP not binding).
//   - out_kernel: r13 bijective XCD-chunked swizzle kept (-4.6 us).
//   All-fp16, XOR k-chunk swizzle (0 bank conflicts on GEMM path).

#define NB 8
#define NL 2048
#define NC 512
#define NCI 256

using f16x8 = __attribute__((ext_vector_type(8))) _Float16;
using f32x4 = __attribute__((ext_vector_type(4))) float;
typedef unsigned short u16;

__device__ __forceinline__ u16 f16b(float x) {
    _Float16 h = (_Float16)x;
    return __builtin_bit_cast(u16, h);
}
__device__ __forceinline__ float f16tof(u16 u) {
    return (float)__builtin_bit_cast(_Float16, u);
}
__device__ __forceinline__ void gload16(const void* g, void* l) {
    __builtin_amdgcn_global_load_lds((__attribute__((address_space(1))) void*)g,
                                     (__attribute__((address_space(3))) void*)l,
                                     16, 0, 0);
}

// ---- cvt: X fp32 -> fp16 --------------------------------------------------
__global__ __launch_bounds__(256) void cvt_x_kernel(const float* __restrict__ X,
                                                    u16* __restrict__ Xf)
{
    size_t i = (size_t)blockIdx.x * 256 + threadIdx.x;   // per 8 elements
    const float4* X4 = (const float4*)X;
    float4 a = X4[2 * i], b = X4[2 * i + 1];
    u16 o[8] = {f16b(a.x), f16b(a.y), f16b(a.z), f16b(a.w),
                f16b(b.x), f16b(b.y), f16b(b.z), f16b(b.w)};
    ((uint4*)Xf)[i] = *(const uint4*)o;
}

// ---- cvt: transpose weights to [n][k] fp16 --------------------------------
__global__ __launch_bounds__(256) void cvt_w_kernel(
    const float* __restrict__ Wx, const float* __restrict__ Wy, const float* __restrict__ Wo,
    u16* __restrict__ WxT, u16* __restrict__ WyT, u16* __restrict__ WoT)
{
    const int bid = blockIdx.x, t = threadIdx.x;
#pragma unroll
    for (int kk = 0; kk < 2; ++kk) {
        const int k = t + kk * 256;
        if (bid < 256)      WxT[(size_t)bid * NC + k] = f16b(Wx[(size_t)k * NCI + bid]);
        else if (bid < 512) WyT[(size_t)(bid - 256) * NC + k] = f16b(Wy[(size_t)k * NCI + (bid - 256)]);
        else                WoT[(size_t)(bid - 512) * NC + k] = f16b(Wo[(size_t)k * NC + (bid - 512)]);
    }
}

// ---- projections: grid (128, 8); cb 0-1 xp, 2-3 yp, 4-7 op (transposed) ----
__global__ __launch_bounds__(256) void proj_kernel(
    const u16* __restrict__ Xf,
    const u16* __restrict__ WxT, const u16* __restrict__ WyT, const u16* __restrict__ WoT,
    const float* __restrict__ bx, const float* __restrict__ by, const float* __restrict__ bo,
    u16* __restrict__ xp, u16* __restrict__ yp, u16* __restrict__ opT)
{
    __shared__ __align__(16) u16 SM[17408];   // As 8192 + Bs 8192; Ts reuse 128x136
    u16* As = SM;
    u16* Bs = SM + 8192;

    const int tid = threadIdx.x;
    const int w = tid >> 6, lane = tid & 63;
    const int row0 = blockIdx.x * 128;
    const int cb = blockIdx.y;

    const u16* W; const float* bias; int n0, path;
    if (cb < 2)      { path = 0; n0 = cb * 128;       W = WxT; bias = bx; }
    else if (cb < 4) { path = 1; n0 = (cb - 2) * 128; W = WyT; bias = by; }
    else             { path = 2; n0 = (cb - 4) * 128; W = WoT; bias = bo; }

    f32x4 acc[4][4] = {};
    const int wm = (w & 1) * 64, wn = (w >> 1) * 64;
    const int fr = lane & 15, fq = lane >> 4;

    for (int k0 = 0; k0 < NC; k0 += 64) {
#pragma unroll
        for (int pass = 0; pass < 4; ++pass) {
            const int cbase = pass * 256 + w * 64;   // wave-uniform
            const int chunk = cbase + lane;
            const int r = chunk >> 3;
            const int kc = (chunk & 7) ^ (r & 7);    // XOR-swizzled k-chunk
            gload16(Xf + (size_t)(row0 + r) * NC + k0 + kc * 8, (char*)As + cbase * 16);
            gload16(W  + (size_t)(n0  + r) * NC + k0 + kc * 8, (char*)Bs + cbase * 16);
        }
        __syncthreads();
        f16x8 a[4][2], b[4][2];
#pragma unroll
        for (int mi = 0; mi < 4; ++mi)
#pragma unroll
            for (int kt = 0; kt < 2; ++kt)
                a[mi][kt] = *(const f16x8*)&As[(wm + mi * 16 + fr) * 64 + ((kt * 4 + fq) ^ (fr & 7)) * 8];
#pragma unroll
        for (int ni = 0; ni < 4; ++ni)
#pragma unroll
            for (int kt = 0; kt < 2; ++kt)
                b[ni][kt] = *(const f16x8*)&Bs[(wn + ni * 16 + fr) * 64 + ((kt * 4 + fq) ^ (fr & 7)) * 8];
#pragma unroll
        for (int kt = 0; kt < 2; ++kt)
#pragma unroll
            for (int mi = 0; mi < 4; ++mi)
#pragma unroll
                for (int ni = 0; ni < 4; ++ni)
                    acc[mi][ni] = __builtin_amdgcn_mfma_f32_16x16x32_f16(a[mi][kt], b[ni][kt], acc[mi][ni], 0, 0, 0);
        __syncthreads();
    }

    if (path != 2) {
        u16* O = (path == 0) ? xp : yp;
#pragma unroll
        for (int mi = 0; mi < 4; ++mi) {
            const int grow = row0 + wm + mi * 16 + fq * 4;
#pragma unroll
            for (int ni = 0; ni < 4; ++ni) {
                const int gcol = n0 + wn + ni * 16 + fr;
                const float bv = bias[gcol];
#pragma unroll
                for (int r = 0; r < 4; ++r)
                    O[(size_t)(grow + r) * NCI + gcol] = f16b(acc[mi][ni][r] + bv);
            }
        }
    } else {
        u16* Ts = SM;   // 128 x 136 fp16 transpose staging
#pragma unroll
        for (int mi = 0; mi < 4; ++mi) {
            const int mb = wm + mi * 16 + fq * 4;
#pragma unroll
            for (int ni = 0; ni < 4; ++ni) {
                const int nl_ = wn + ni * 16 + fr;
                const float bv = bias[n0 + nl_];
#pragma unroll
                for (int r = 0; r < 4; ++r)
                    Ts[nl_ * 136 + mb + r] = f16b(acc[mi][ni][r] + bv);
            }
        }
        __syncthreads();
        const int b = row0 >> 11, m0 = row0 & 2047;
        u16* dst = opT + (size_t)b * NC * NL + (size_t)n0 * NL + m0;
        for (int i = tid; i < 128 * 16; i += 256) {
            const int c = i >> 4, ch = i & 15;
            uint4 v = *(const uint4*)&Ts[c * 136 + ch * 8];
            *(uint4*)&dst[(size_t)c * NL + ch * 8] = v;
        }
    }
}

// ---- FUSED score+softmax --------------------------------------------------
// Round 15: grid (32,32), 512 thr / 8 waves. Block = one 64x64 (l,m) tile.
// Batches in 2 groups of 4 resident in LDS; wave w computes batch w&3 on
// n-half w>>2. 8 big stages (8 gload16/thread each) vs r13's 16. Softmax
// via 65-padded LDS exchange.
__global__ __launch_bounds__(512, 4) void score_softmax_kernel(
    const u16* __restrict__ xp, const u16* __restrict__ yp, u16* __restrict__ ATT)
{
    // staging: A[bb] at bb*4096 (64x64 u16), B[bb] at 16384+bb*4096 (64 KB)
    // exchange: [row][col pad 65][b] u16 -> 33280 u16 = 66.5 KB total
    __shared__ __align__(16) u16 SM[33280];
    const int tid = threadIdx.x;
    const int w = tid >> 6, lane = tid & 63;
    const int row0 = blockIdx.x * 64, col0 = blockIdx.y * 64;
    const int bb = w & 3, nh = w >> 2;
    const int fr = lane & 15, fq = lane >> 4;

    const int rs = (tid >> 3) & 63;          // staging row 0..63
    const int jj = (tid & 7) ^ (rs & 7);     // XOR-swizzled k-chunk

    unsigned sv[2][16];   // [g][mi*4+ni*2+rp] packed fp16 pairs

#pragma unroll
    for (int g = 0; g < 2; ++g) {
        f32x4 acc[4][2] = {};
#pragma unroll
        for (int s = 0; s < 4; ++s) {
            const int k0 = s * 64;
            // stage 4 batches' A+B 64x64 k-chunk tiles (4096 chunks, 8 passes)
#pragma unroll
            for (int pass = 0; pass < 8; ++pass) {
                const int ab = pass >> 2, b2 = pass & 3;   // wave-uniform
                const u16* src = (ab ? yp : xp)
                    + (size_t)(g * 4 + b2) * NL * NCI
                    + (size_t)((ab ? col0 : row0) + rs) * NCI + k0 + jj * 8;
                gload16(src, (char*)SM + pass * 8192 + tid * 16);
            }
            __syncthreads();
#pragma unroll
            for (int kt = 0; kt < 2; ++kt) {
                const int coff = ((kt * 4 + fq) ^ (fr & 7)) * 8;
                f16x8 af[4], bf[2];
#pragma unroll
                for (int mi = 0; mi < 4; ++mi)
                    af[mi] = *(const f16x8*)&SM[bb * 4096 + (mi * 16 + fr) * 64 + coff];
#pragma unroll
                for (int ni = 0; ni < 2; ++ni)
                    bf[ni] = *(const f16x8*)&SM[16384 + bb * 4096 + (nh * 32 + ni * 16 + fr) * 64 + coff];
#pragma unroll
                for (int mi = 0; mi < 4; ++mi)
#pragma unroll
                    for (int ni = 0; ni < 2; ++ni)
                        acc[mi][ni] = __builtin_amdgcn_mfma_f32_16x16x32_f16(af[mi], bf[ni], acc[mi][ni], 0, 0, 0);
            }
            __syncthreads();
        }
#pragma unroll
        for (int mi = 0; mi < 4; ++mi)
#pragma unroll
            for (int ni = 0; ni < 2; ++ni) {
                sv[g][mi * 4 + ni * 2 + 0] = (unsigned)f16b(acc[mi][ni][0]) | ((unsigned)f16b(acc[mi][ni][1]) << 16);
                sv[g][mi * 4 + ni * 2 + 1] = (unsigned)f16b(acc[mi][ni][2]) | ((unsigned)f16b(acc[mi][ni][3]) << 16);
            }
    }

    // exchange: scores -> SM[(row*65+col)*8 + b] (last stage barrier covers reads)
#pragma unroll
    for (int g = 0; g < 2; ++g)
#pragma unroll
        for (int mi = 0; mi < 4; ++mi)
#pragma unroll
            for (int ni = 0; ni < 2; ++ni)
#pragma unroll
                for (int rp = 0; rp < 2; ++rp) {
                    const unsigned u = sv[g][mi * 4 + ni * 2 + rp];
                    const int r_ = mi * 16 + fq * 4 + rp * 2;
                    const int c_ = nh * 32 + ni * 16 + fr;
                    SM[(r_ * 65 + c_) * 8 + g * 4 + bb]         = (u16)(u & 0xFFFF);
                    SM[((r_ + 1) * 65 + c_) * 8 + g * 4 + bb]   = (u16)(u >> 16);
                }
    __syncthreads();

    // softmax over b (8 contiguous u16 per slot = one b128 read), write ATT
#pragma unroll
    for (int j = 0; j < 8; ++j) {
        const int row = j * 8 + w;             // slot row 0..63
        const int col = lane;                  // slot col 0..63
        const uint4 v = *(const uint4*)&SM[(row * 65 + col) * 8];
        float f[NB];
        f[0] = f16tof((u16)(v.x & 0xFFFF)); f[1] = f16tof((u16)(v.x >> 16));
        f[2] = f16tof((u16)(v.y & 0xFFFF)); f[3] = f16tof((u16)(v.y >> 16));
        f[4] = f16tof((u16)(v.z & 0xFFFF)); f[5] = f16tof((u16)(v.z >> 16));
        f[6] = f16tof((u16)(v.w & 0xFFFF)); f[7] = f16tof((u16)(v.w >> 16));
        float m = f[0];
#pragma unroll
        for (int b = 1; b < NB; ++b) m = fmaxf(m, f[b]);
        float ssum = 0.f;
#pragma unroll
        for (int b = 0; b < NB; ++b) { f[b] = __expf(f[b] - m); ssum += f[b]; }
        const float inv = 1.f / ssum;
        const size_t go = (size_t)(row0 + row) * NL + col0 + col;
#pragma unroll
        for (int b = 0; b < NB; ++b)
            ATT[(size_t)b * NL * NL + go] = f16b(f[b] * inv);
    }
}

// ---- out: out[b] = X[b] + attn[b] @ op[b], 512 thr, issue-early dbuf -------
// r13 bijective XCD-chunked swizzle (512 blocks, 512%8==0) — each XCD owns
// one batch: opT[b] (2MB) L2-resident, ATT[b] panels L2-reused.
__global__ __launch_bounds__(512) void out_kernel(
    const u16* __restrict__ ATT, const u16* __restrict__ opT,
    const float* __restrict__ X, float* __restrict__ Out)
{
    __shared__ __align__(16) u16 As[2][8192], Bs[2][8192];   // 128 x 64 each, x2
    const int tid = threadIdx.x;
    const int w = tid >> 6, lane = tid & 63;

    // linear dispatch id (x-fastest) -> XCD-chunked remap (bijective: 512%8==0)
    const int id  = blockIdx.x + 16 * (blockIdx.y + 4 * blockIdx.z);
    const int nid = (id & 7) * 64 + (id >> 3);   // chunk = 512/8 = 64
    const int bx  = nid & 15;                    // row tile 0..15
    const int by  = (nid >> 4) & 3;              // col tile 0..3
    const int b   = nid >> 6;                    // batch 0..7

    const int row0 = bx * 128, col0 = by * 128;
    const u16* Aatt = ATT + (size_t)b * NL * NL;
    const u16* Bsrc = opT + (size_t)b * NC * NL;

    f32x4 acc[4][2] = {};
    const int wm = (w & 1) * 64, wn = (w >> 1) * 32;
    const int fr = lane & 15, fq = lane >> 4;

    // staging helper (as lambda): stage K-chunk k0 into buffer bu
    auto stage = [&](int k0, int bu) {
#pragma unroll
        for (int pass = 0; pass < 2; ++pass) {
            const int cbase = pass * 512 + w * 64;   // wave-uniform
            const int chunk = cbase + lane;
            const int r = chunk >> 3;
            const int kc = (chunk & 7) ^ (r & 7);
            gload16(Aatt + (size_t)(row0 + r) * NL + k0 + kc * 8, (char*)&As[bu][0] + cbase * 16);
            gload16(Bsrc + (size_t)(col0 + r) * NL + k0 + kc * 8, (char*)&Bs[bu][0] + cbase * 16);
        }
    };

    stage(0, 0);
    int bu = 0;
    for (int it = 0; it < NL / 64; ++it) {
        __syncthreads();                         // own vmcnt(0) drained -> buf[bu] ready
        if (it + 1 < NL / 64) stage((it + 1) * 64, bu ^ 1);   // issue early, fly during compute
        f16x8 af[4][2], bf[2][2];
#pragma unroll
        for (int mi = 0; mi < 4; ++mi)
#pragma unroll
            for (int kt = 0; kt < 2; ++kt)
                af[mi][kt] = *(const f16x8*)&As[bu][(wm + mi * 16 + fr) * 64 + ((kt * 4 + fq) ^ (fr & 7)) * 8];
#pragma unroll
        for (int ni = 0; ni < 2; ++ni)
#pragma unroll
            for (int kt = 0; kt < 2; ++kt)
                bf[ni][kt] = *(const f16x8*)&Bs[bu][(wn + ni * 16 + fr) * 64 + ((kt * 4 + fq) ^ (fr & 7)) * 8];
#pragma unroll
        for (int kt = 0; kt < 2; ++kt)
#pragma unroll
            for (int mi = 0; mi < 4; ++mi)
#pragma unroll
                for (int ni = 0; ni < 2; ++ni)
                    acc[mi][ni] = __builtin_amdgcn_mfma_f32_16x16x32_f16(af[mi][kt], bf[ni][kt], acc[mi][ni], 0, 0, 0);
        bu ^= 1;
    }
    const size_t ob = (size_t)b * NL * NC;
#pragma unroll
    for (int mi = 0; mi < 4; ++mi) {
        const int gr = row0 + wm + mi * 16 + fq * 4;
#pragma unroll
        for (int ni = 0; ni < 2; ++ni) {
            const int gc = col0 + wn + ni * 16 + fr;
#pragma unroll
            for (int r = 0; r < 4; ++r) {
                const size_t o = ob + (size_t)(gr + r) * NC + gc;
                Out[o] = X[o] + acc[mi][ni][r];
            }
        }
    }
}

extern "C" void kernel_launch(void* const* d_in, const int* in_sizes, int n_in,
                              void* d_out, int out_size, void* d_ws, size_t ws_size,
                              hipStream_t stream)
{
    const float* X  = (const float*)d_in[0];
    const float* Wx = (const float*)d_in[1];
    const float* bx = (const float*)d_in[2];
    const float* Wy = (const float*)d_in[3];
    const float* by = (const float*)d_in[4];
    const float* Wo = (const float*)d_in[5];
    const float* bo = (const float*)d_in[6];
    float* out = (float*)d_out;

    // Workspace (~97 MB): ATT fp16 [0,64MB); Xf16 (16MB) overlaps ATT[0:16MB) —
    // dead (proj done) before score_softmax writes ATT (stream-ordered).
    char* ws = (char*)d_ws;
    u16* ATT = (u16*)ws;
    u16* Xf  = (u16*)ws;
    char* p = ws + 67108864;
    u16* xp  = (u16*)p; p += 8388608;
    u16* yp  = (u16*)p; p += 8388608;
    u16* opT = (u16*)p; p += 16777216;
    u16* WxT = (u16*)p; p += 262144;
    u16* WyT = (u16*)p; p += 262144;
    u16* WoT = (u16*)p; p += 524288;

    cvt_x_kernel<<<4096, 256, 0, stream>>>(X, Xf);
    cvt_w_kernel<<<1024, 256, 0, stream>>>(Wx, Wy, Wo, WxT, WyT, WoT);
    proj_kernel<<<dim3(128, 8), 256, 0, stream>>>(Xf, WxT, WyT, WoT, bx, by, bo, xp, yp, opT);
    score_softmax_kernel<<<dim3(32, 32), 512, 0, stream>>>(xp, yp, ATT);
    out_kernel<<<dim3(16, 4, NB), 512, 0, stream>>>(ATT, opT, X, out);
}

// Round 10
// 200.942 us; speedup vs baseline: 1.0363x; 1.0363x over previous
//
#include <hip/hip_runtime.h>

// NonLocalBlock B=8, L=2048, C=512, CI=256 (fp32 in/out).
// Round 16:
//   - score_softmax: keep r15 batch-parallel structure (within-run WIN
//     51.4 -> 46.4 us; exchange conflicts are LDS-BW floor, not fixable).
//   - out_kernel: serial BK=128 stacked-64-half staging (r9->r10 proven
//     pattern: half the barrier-drain events, 2x loads in flight, same
//     64 KB LDS -> 2 blocks/CU unchanged). Replaces issue-early BK=64 dbuf.
//     Zero-conflict read geometry identical to r10. XCD swizzle kept.
//   All-fp16, XOR k-chunk swizzle.

#define NB 8
#define NL 2048
#define NC 512
#define NCI 256

using f16x8 = __attribute__((ext_vector_type(8))) _Float16;
using f32x4 = __attribute__((ext_vector_type(4))) float;
typedef unsigned short u16;

__device__ __forceinline__ u16 f16b(float x) {
    _Float16 h = (_Float16)x;
    return __builtin_bit_cast(u16, h);
}
__device__ __forceinline__ float f16tof(u16 u) {
    return (float)__builtin_bit_cast(_Float16, u);
}
__device__ __forceinline__ void gload16(const void* g, void* l) {
    __builtin_amdgcn_global_load_lds((__attribute__((address_space(1))) void*)g,
                                     (__attribute__((address_space(3))) void*)l,
                                     16, 0, 0);
}

// ---- cvt: X fp32 -> fp16 --------------------------------------------------
__global__ __launch_bounds__(256) void cvt_x_kernel(const float* __restrict__ X,
                                                    u16* __restrict__ Xf)
{
    size_t i = (size_t)blockIdx.x * 256 + threadIdx.x;   // per 8 elements
    const float4* X4 = (const float4*)X;
    float4 a = X4[2 * i], b = X4[2 * i + 1];
    u16 o[8] = {f16b(a.x), f16b(a.y), f16b(a.z), f16b(a.w),
                f16b(b.x), f16b(b.y), f16b(b.z), f16b(b.w)};
    ((uint4*)Xf)[i] = *(const uint4*)o;
}

// ---- cvt: transpose weights to [n][k] fp16 --------------------------------
__global__ __launch_bounds__(256) void cvt_w_kernel(
    const float* __restrict__ Wx, const float* __restrict__ Wy, const float* __restrict__ Wo,
    u16* __restrict__ WxT, u16* __restrict__ WyT, u16* __restrict__ WoT)
{
    const int bid = blockIdx.x, t = threadIdx.x;
#pragma unroll
    for (int kk = 0; kk < 2; ++kk) {
        const int k = t + kk * 256;
        if (bid < 256)      WxT[(size_t)bid * NC + k] = f16b(Wx[(size_t)k * NCI + bid]);
        else if (bid < 512) WyT[(size_t)(bid - 256) * NC + k] = f16b(Wy[(size_t)k * NCI + (bid - 256)]);
        else                WoT[(size_t)(bid - 512) * NC + k] = f16b(Wo[(size_t)k * NC + (bid - 512)]);
    }
}

// ---- projections: grid (128, 8); cb 0-1 xp, 2-3 yp, 4-7 op (transposed) ----
__global__ __launch_bounds__(256) void proj_kernel(
    const u16* __restrict__ Xf,
    const u16* __restrict__ WxT, const u16* __restrict__ WyT, const u16* __restrict__ WoT,
    const float* __restrict__ bx, const float* __restrict__ by, const float* __restrict__ bo,
    u16* __restrict__ xp, u16* __restrict__ yp, u16* __restrict__ opT)
{
    __shared__ __align__(16) u16 SM[17408];   // As 8192 + Bs 8192; Ts reuse 128x136
    u16* As = SM;
    u16* Bs = SM + 8192;

    const int tid = threadIdx.x;
    const int w = tid >> 6, lane = tid & 63;
    const int row0 = blockIdx.x * 128;
    const int cb = blockIdx.y;

    const u16* W; const float* bias; int n0, path;
    if (cb < 2)      { path = 0; n0 = cb * 128;       W = WxT; bias = bx; }
    else if (cb < 4) { path = 1; n0 = (cb - 2) * 128; W = WyT; bias = by; }
    else             { path = 2; n0 = (cb - 4) * 128; W = WoT; bias = bo; }

    f32x4 acc[4][4] = {};
    const int wm = (w & 1) * 64, wn = (w >> 1) * 64;
    const int fr = lane & 15, fq = lane >> 4;

    for (int k0 = 0; k0 < NC; k0 += 64) {
#pragma unroll
        for (int pass = 0; pass < 4; ++pass) {
            const int cbase = pass * 256 + w * 64;   // wave-uniform
            const int chunk = cbase + lane;
            const int r = chunk >> 3;
            const int kc = (chunk & 7) ^ (r & 7);    // XOR-swizzled k-chunk
            gload16(Xf + (size_t)(row0 + r) * NC + k0 + kc * 8, (char*)As + cbase * 16);
            gload16(W  + (size_t)(n0  + r) * NC + k0 + kc * 8, (char*)Bs + cbase * 16);
        }
        __syncthreads();
        f16x8 a[4][2], b[4][2];
#pragma unroll
        for (int mi = 0; mi < 4; ++mi)
#pragma unroll
            for (int kt = 0; kt < 2; ++kt)
                a[mi][kt] = *(const f16x8*)&As[(wm + mi * 16 + fr) * 64 + ((kt * 4 + fq) ^ (fr & 7)) * 8];
#pragma unroll
        for (int ni = 0; ni < 4; ++ni)
#pragma unroll
            for (int kt = 0; kt < 2; ++kt)
                b[ni][kt] = *(const f16x8*)&Bs[(wn + ni * 16 + fr) * 64 + ((kt * 4 + fq) ^ (fr & 7)) * 8];
#pragma unroll
        for (int kt = 0; kt < 2; ++kt)
#pragma unroll
            for (int mi = 0; mi < 4; ++mi)
#pragma unroll
                for (int ni = 0; ni < 4; ++ni)
                    acc[mi][ni] = __builtin_amdgcn_mfma_f32_16x16x32_f16(a[mi][kt], b[ni][kt], acc[mi][ni], 0, 0, 0);
        __syncthreads();
    }

    if (path != 2) {
        u16* O = (path == 0) ? xp : yp;
#pragma unroll
        for (int mi = 0; mi < 4; ++mi) {
            const int grow = row0 + wm + mi * 16 + fq * 4;
#pragma unroll
            for (int ni = 0; ni < 4; ++ni) {
                const int gcol = n0 + wn + ni * 16 + fr;
                const float bv = bias[gcol];
#pragma unroll
                for (int r = 0; r < 4; ++r)
                    O[(size_t)(grow + r) * NCI + gcol] = f16b(acc[mi][ni][r] + bv);
            }
        }
    } else {
        u16* Ts = SM;   // 128 x 136 fp16 transpose staging
#pragma unroll
        for (int mi = 0; mi < 4; ++mi) {
            const int mb = wm + mi * 16 + fq * 4;
#pragma unroll
            for (int ni = 0; ni < 4; ++ni) {
                const int nl_ = wn + ni * 16 + fr;
                const float bv = bias[n0 + nl_];
#pragma unroll
                for (int r = 0; r < 4; ++r)
                    Ts[nl_ * 136 + mb + r] = f16b(acc[mi][ni][r] + bv);
            }
        }
        __syncthreads();
        const int b = row0 >> 11, m0 = row0 & 2047;
        u16* dst = opT + (size_t)b * NC * NL + (size_t)n0 * NL + m0;
        for (int i = tid; i < 128 * 16; i += 256) {
            const int c = i >> 4, ch = i & 15;
            uint4 v = *(const uint4*)&Ts[c * 136 + ch * 8];
            *(uint4*)&dst[(size_t)c * NL + ch * 8] = v;
        }
    }
}

// ---- FUSED score+softmax --------------------------------------------------
// r15: grid (32,32), 512 thr / 8 waves. Block = one 64x64 (l,m) tile.
// Batches in 2 groups of 4 resident in LDS; wave w computes batch w&3 on
// n-half w>>2. 8 big stages (8 gload16/thread each). Softmax via 65-padded
// LDS exchange.
__global__ __launch_bounds__(512, 4) void score_softmax_kernel(
    const u16* __restrict__ xp, const u16* __restrict__ yp, u16* __restrict__ ATT)
{
    // staging: A[bb] at bb*4096 (64x64 u16), B[bb] at 16384+bb*4096 (64 KB)
    // exchange: [row][col pad 65][b] u16 -> 33280 u16 = 66.5 KB total
    __shared__ __align__(16) u16 SM[33280];
    const int tid = threadIdx.x;
    const int w = tid >> 6, lane = tid & 63;
    const int row0 = blockIdx.x * 64, col0 = blockIdx.y * 64;
    const int bb = w & 3, nh = w >> 2;
    const int fr = lane & 15, fq = lane >> 4;

    const int rs = (tid >> 3) & 63;          // staging row 0..63
    const int jj = (tid & 7) ^ (rs & 7);     // XOR-swizzled k-chunk

    unsigned sv[2][16];   // [g][mi*4+ni*2+rp] packed fp16 pairs

#pragma unroll
    for (int g = 0; g < 2; ++g) {
        f32x4 acc[4][2] = {};
#pragma unroll
        for (int s = 0; s < 4; ++s) {
            const int k0 = s * 64;
            // stage 4 batches' A+B 64x64 k-chunk tiles (4096 chunks, 8 passes)
#pragma unroll
            for (int pass = 0; pass < 8; ++pass) {
                const int ab = pass >> 2, b2 = pass & 3;   // wave-uniform
                const u16* src = (ab ? yp : xp)
                    + (size_t)(g * 4 + b2) * NL * NCI
                    + (size_t)((ab ? col0 : row0) + rs) * NCI + k0 + jj * 8;
                gload16(src, (char*)SM + pass * 8192 + tid * 16);
            }
            __syncthreads();
#pragma unroll
            for (int kt = 0; kt < 2; ++kt) {
                const int coff = ((kt * 4 + fq) ^ (fr & 7)) * 8;
                f16x8 af[4], bf[2];
#pragma unroll
                for (int mi = 0; mi < 4; ++mi)
                    af[mi] = *(const f16x8*)&SM[bb * 4096 + (mi * 16 + fr) * 64 + coff];
#pragma unroll
                for (int ni = 0; ni < 2; ++ni)
                    bf[ni] = *(const f16x8*)&SM[16384 + bb * 4096 + (nh * 32 + ni * 16 + fr) * 64 + coff];
#pragma unroll
                for (int mi = 0; mi < 4; ++mi)
#pragma unroll
                    for (int ni = 0; ni < 2; ++ni)
                        acc[mi][ni] = __builtin_amdgcn_mfma_f32_16x16x32_f16(af[mi], bf[ni], acc[mi][ni], 0, 0, 0);
            }
            __syncthreads();
        }
#pragma unroll
        for (int mi = 0; mi < 4; ++mi)
#pragma unroll
            for (int ni = 0; ni < 2; ++ni) {
                sv[g][mi * 4 + ni * 2 + 0] = (unsigned)f16b(acc[mi][ni][0]) | ((unsigned)f16b(acc[mi][ni][1]) << 16);
                sv[g][mi * 4 + ni * 2 + 1] = (unsigned)f16b(acc[mi][ni][2]) | ((unsigned)f16b(acc[mi][ni][3]) << 16);
            }
    }

    // exchange: scores -> SM[(row*65+col)*8 + b] (last stage barrier covers reads)
#pragma unroll
    for (int g = 0; g < 2; ++g)
#pragma unroll
        for (int mi = 0; mi < 4; ++mi)
#pragma unroll
            for (int ni = 0; ni < 2; ++ni)
#pragma unroll
                for (int rp = 0; rp < 2; ++rp) {
                    const unsigned u = sv[g][mi * 4 + ni * 2 + rp];
                    const int r_ = mi * 16 + fq * 4 + rp * 2;
                    const int c_ = nh * 32 + ni * 16 + fr;
                    SM[(r_ * 65 + c_) * 8 + g * 4 + bb]         = (u16)(u & 0xFFFF);
                    SM[((r_ + 1) * 65 + c_) * 8 + g * 4 + bb]   = (u16)(u >> 16);
                }
    __syncthreads();

    // softmax over b (8 contiguous u16 per slot = one b128 read), write ATT
#pragma unroll
    for (int j = 0; j < 8; ++j) {
        const int row = j * 8 + w;             // slot row 0..63
        const int col = lane;                  // slot col 0..63
        const uint4 v = *(const uint4*)&SM[(row * 65 + col) * 8];
        float f[NB];
        f[0] = f16tof((u16)(v.x & 0xFFFF)); f[1] = f16tof((u16)(v.x >> 16));
        f[2] = f16tof((u16)(v.y & 0xFFFF)); f[3] = f16tof((u16)(v.y >> 16));
        f[4] = f16tof((u16)(v.z & 0xFFFF)); f[5] = f16tof((u16)(v.z >> 16));
        f[6] = f16tof((u16)(v.w & 0xFFFF)); f[7] = f16tof((u16)(v.w >> 16));
        float m = f[0];
#pragma unroll
        for (int b = 1; b < NB; ++b) m = fmaxf(m, f[b]);
        float ssum = 0.f;
#pragma unroll
        for (int b = 0; b < NB; ++b) { f[b] = __expf(f[b] - m); ssum += f[b]; }
        const float inv = 1.f / ssum;
        const size_t go = (size_t)(row0 + row) * NL + col0 + col;
#pragma unroll
        for (int b = 0; b < NB; ++b)
            ATT[(size_t)b * NL * NL + go] = f16b(f[b] * inv);
    }
}

// ---- out: out[b] = X[b] + attn[b] @ op[b], 512 thr ------------------------
// Round 16: serial BK=128 staged as stacked 64-k halves (r10 pattern):
// 16 stages of 8 gload16/thread, 64 KB LDS single-buffer -> 2 blocks/CU
// (same as dbuf BK=64), half the barrier-drain events, 2x loads in flight.
// r13 bijective XCD-chunked swizzle kept.
__global__ __launch_bounds__(512) void out_kernel(
    const u16* __restrict__ ATT, const u16* __restrict__ opT,
    const float* __restrict__ X, float* __restrict__ Out)
{
    __shared__ __align__(16) u16 As[16384], Bs[16384];   // 2x(128x64) u16 each
    const int tid = threadIdx.x;
    const int w = tid >> 6, lane = tid & 63;

    // linear dispatch id (x-fastest) -> XCD-chunked remap (bijective: 512%8==0)
    const int id  = blockIdx.x + 16 * (blockIdx.y + 4 * blockIdx.z);
    const int nid = (id & 7) * 64 + (id >> 3);   // chunk = 512/8 = 64
    const int bx  = nid & 15;                    // row tile 0..15
    const int by  = (nid >> 4) & 3;              // col tile 0..3
    const int b   = nid >> 6;                    // batch 0..7

    const int row0 = bx * 128, col0 = by * 128;
    const u16* Aatt = ATT + (size_t)b * NL * NL;
    const u16* Bsrc = opT + (size_t)b * NC * NL;

    f32x4 acc[4][2] = {};
    const int wm = (w & 1) * 64, wn = (w >> 1) * 32;
    const int fr = lane & 15, fq = lane >> 4;

    for (int it = 0; it < NL / 128; ++it) {
        const int k0 = it * 128;
        // stage A,B 128x128 as stacked 64-k halves (2048 chunks, 4 passes)
#pragma unroll
        for (int pass = 0; pass < 4; ++pass) {
            const int c = pass * 512 + tid;
            const int kh = c >> 10;              // 0..1 (1024 chunks per half)
            const int r = (c >> 3) & 127;        // row 0..127
            const int jj = (c & 7) ^ (r & 7);    // XOR-swizzled k-chunk
            const int srck = k0 + kh * 64 + jj * 8;
            gload16(Aatt + (size_t)(row0 + r) * NL + srck, (char*)As + c * 16);
            gload16(Bsrc + (size_t)(col0 + r) * NL + srck, (char*)Bs + c * 16);
        }
        __syncthreads();
#pragma unroll
        for (int kh = 0; kh < 2; ++kh)
#pragma unroll
            for (int kt = 0; kt < 2; ++kt) {
                const int hb = kh * 8192;
                const int coff = ((kt * 4 + fq) ^ (fr & 7)) * 8;
                f16x8 af[4], bf[2];
#pragma unroll
                for (int mi = 0; mi < 4; ++mi)
                    af[mi] = *(const f16x8*)&As[hb + (wm + mi * 16 + fr) * 64 + coff];
#pragma unroll
                for (int ni = 0; ni < 2; ++ni)
                    bf[ni] = *(const f16x8*)&Bs[hb + (wn + ni * 16 + fr) * 64 + coff];
#pragma unroll
                for (int mi = 0; mi < 4; ++mi)
#pragma unroll
                    for (int ni = 0; ni < 2; ++ni)
                        acc[mi][ni] = __builtin_amdgcn_mfma_f32_16x16x32_f16(af[mi], bf[ni], acc[mi][ni], 0, 0, 0);
            }
        __syncthreads();
    }
    const size_t ob = (size_t)b * NL * NC;
#pragma unroll
    for (int mi = 0; mi < 4; ++mi) {
        const int gr = row0 + wm + mi * 16 + fq * 4;
#pragma unroll
        for (int ni = 0; ni < 2; ++ni) {
            const int gc = col0 + wn + ni * 16 + fr;
#pragma unroll
            for (int r = 0; r < 4; ++r) {
                const size_t o = ob + (size_t)(gr + r) * NC + gc;
                Out[o] = X[o] + acc[mi][ni][r];
            }
        }
    }
}

extern "C" void kernel_launch(void* const* d_in, const int* in_sizes, int n_in,
                              void* d_out, int out_size, void* d_ws, size_t ws_size,
                              hipStream_t stream)
{
    const float* X  = (const float*)d_in[0];
    const float* Wx = (const float*)d_in[1];
    const float* bx = (const float*)d_in[2];
    const float* Wy = (const float*)d_in[3];
    const float* by = (const float*)d_in[4];
    const float* Wo = (const float*)d_in[5];
    const float* bo = (const float*)d_in[6];
    float* out = (float*)d_out;

    // Workspace (~97 MB): ATT fp16 [0,64MB); Xf16 (16MB) overlaps ATT[0:16MB) —
    // dead (proj done) before score_softmax writes ATT (stream-ordered).
    char* ws = (char*)d_ws;
    u16* ATT = (u16*)ws;
    u16* Xf  = (u16*)ws;
    char* p = ws + 67108864;
    u16* xp  = (u16*)p; p += 8388608;
    u16* yp  = (u16*)p; p += 8388608;
    u16* opT = (u16*)p; p += 16777216;
    u16* WxT = (u16*)p; p += 262144;
    u16* WyT = (u16*)p; p += 262144;
    u16* WoT = (u16*)p; p += 524288;

    cvt_x_kernel<<<4096, 256, 0, stream>>>(X, Xf);
    cvt_w_kernel<<<1024, 256, 0, stream>>>(Wx, Wy, Wo, WxT, WyT, WoT);
    proj_kernel<<<dim3(128, 8), 256, 0, stream>>>(Xf, WxT, WyT, WoT, bx, by, bo, xp, yp, opT);
    score_softmax_kernel<<<dim3(32, 32), 512, 0, stream>>>(xp, yp, ATT);
    out_kernel<<<dim3(16, 4, NB), 512, 0, stream>>>(ATT, opT, X, out);
}